// Round 6
// baseline (310.519 us; speedup 1.0000x reference)
//
#include <hip/hip_runtime.h>
#include <hip/hip_bf16.h>

typedef __hip_bfloat16 bf16;
typedef float f32x4 __attribute__((ext_vector_type(4)));
typedef short s16x8 __attribute__((ext_vector_type(8)));

// ---------------------------------------------------------------------------
__device__ __forceinline__ void async_load16(const void* g, void* lds) {
  __builtin_amdgcn_global_load_lds(
      (const __attribute__((address_space(1))) void*)g,
      (__attribute__((address_space(3))) void*)lds, 16, 0, 0);
}

#define WAITV(N) asm volatile("s_waitcnt vmcnt(" #N ")" ::: "memory")

// raw barrier with compiler memory fence on both sides
__device__ __forceinline__ void wg_barrier() {
  asm volatile("" ::: "memory");
  __builtin_amdgcn_s_barrier();
  asm volatile("" ::: "memory");
}

__device__ __forceinline__ void store_out(float* p, float v) { *p = v; }
__device__ __forceinline__ void store_out(bf16* p, float v) { *p = __float2bfloat16(v); }

// ---------------------------------------------------------------------------
// C[M,N] = scale*(A[M,K] @ BT[N,K]^T) + bias. bf16 in, f32 acc.
// 128x128 tile, BK=32, 4 waves (2x2 of 64x64), 16x16x32 bf16 MFMA.
// T4 pipeline: 3 LDS buffers, counted vmcnt (never 0 mid-loop), 1 barrier/iter.
//   iter kt: WAITV(4) [tile kt landed; kt+1 in flight] -> barrier
//            -> stage tile kt+2 into buf[(kt+2)%3] (= buf read at kt-1, safe:
//               all its readers crossed this barrier) -> ds_read buf[kt%3]
//            -> MFMA (lgkm auto).
// Ledger/wave (4 loads per stage): pre-wait outstanding = {kt, kt+1} = 8
//   -> WAITV(4) drains tile kt. Tail: kt=nt-1 WAITV(0). Verified nt>=2.
// BIASMODE: 0 none, 1 per-column, 2 per-row.
// SWZ=1: batched, id&7 = batch (XCD pin). SWZ=2: chunked XCD swizzle.
template <typename OutT, int BIASMODE, int SWZ>
__global__ void gemm_bt(const bf16* __restrict__ Ag, const bf16* __restrict__ Bg,
                        OutT* Cg, const float* __restrict__ biasp, float scale,
                        int K, int lda, int ldb, int ldc, int ntx,
                        long long sA, long long sB, long long sC) {
  __shared__ bf16 As[3][128 * 32];
  __shared__ bf16 Bs[3][128 * 32];

  const int id = blockIdx.x;
  int bz = 0, tile;
  if (SWZ == 1) { bz = id & 7; tile = id >> 3; }
  else { const int q = gridDim.x >> 3; tile = (id & 7) * q + (id >> 3); }
  const int tn = tile % ntx, tm = tile / ntx;

  const bf16* A = Ag + bz * sA;
  const bf16* BT = Bg + bz * sB;
  OutT* C = Cg + bz * sC;

  const int t = threadIdx.x;
  const int lane = t & 63;
  const int wid = t >> 6;
  const int wr = wid >> 1, wc = wid & 1;
  const int lo = lane & 15, hi = lane >> 4;

  const int arow0 = tm * 128, brow0 = tn * 128;

  // staging: 2 chunks of 16B per thread per operand (tile row = 64B)
  const int idx0 = t, idx1 = 256 + t;
  const int r0 = idx0 >> 2, c0 = (idx0 & 3) * 8;
  const int r1 = idx1 >> 2, c1 = (idx1 & 3) * 8;
  const bf16* a0 = A + (long long)(arow0 + r0) * lda + c0;
  const bf16* a1 = A + (long long)(arow0 + r1) * lda + c1;
  const bf16* b0 = BT + (long long)(brow0 + r0) * ldb + c0;
  const bf16* b1 = BT + (long long)(brow0 + r1) * ldb + c1;

  auto stage = [&](int k0, bf16* Ad, bf16* Bd) {
    async_load16(a0 + k0, Ad + idx0 * 8);
    async_load16(a1 + k0, Ad + idx1 * 8);
    async_load16(b0 + k0, Bd + idx0 * 8);
    async_load16(b1 + k0, Bd + idx1 * 8);
  };

  f32x4 acc[4][4] = {};
  const int nt = K >> 5;

  // rotating buffer pointers: pR*=read this iter, pN*=next, pS*=stage target
  bf16 *pRA = &As[0][0], *pNA = &As[1][0], *pSA = &As[2][0];
  bf16 *pRB = &Bs[0][0], *pNB = &Bs[1][0], *pSB = &Bs[2][0];

  // prologue: stage tiles 0,1 -> 8 outstanding
  stage(0, pRA, pRB);
  stage(32, pNA, pNB);

  for (int kt = 0; kt < nt; ++kt) {
    if (kt + 1 < nt) WAITV(4); else WAITV(0);
    wg_barrier();
    if (kt + 2 < nt) stage((kt + 2) << 5, pSA, pSB);

    s16x8 a[4], b[4];
#pragma unroll
    for (int m = 0; m < 4; ++m)
      a[m] = *(const s16x8*)&pRA[(wr * 64 + m * 16 + lo) * 32 + hi * 8];
#pragma unroll
    for (int n = 0; n < 4; ++n)
      b[n] = *(const s16x8*)&pRB[(wc * 64 + n * 16 + lo) * 32 + hi * 8];
#pragma unroll
    for (int m = 0; m < 4; ++m)
#pragma unroll
      for (int n = 0; n < 4; ++n)
        acc[m][n] = __builtin_amdgcn_mfma_f32_16x16x32_bf16(a[m], b[n], acc[m][n], 0, 0, 0);

    // rotate: read->retired(stage target next iter), next->read, stage->next
    bf16* tA = pRA; pRA = pNA; pNA = pSA; pSA = tA;
    bf16* tB = pRB; pRB = pNB; pNB = pSB; pSB = tB;
  }

  // C/D layout: col = lane&15, row = (lane>>4)*4 + reg
  float bcol[4] = {0.f, 0.f, 0.f, 0.f};
  if (BIASMODE == 1) {
#pragma unroll
    for (int n = 0; n < 4; ++n)
      bcol[n] = biasp[brow0 + wc * 64 + n * 16 + lo];
  }
#pragma unroll
  for (int m = 0; m < 4; ++m) {
    const int row = arow0 + wr * 64 + m * 16 + hi * 4;
    float br[4] = {0.f, 0.f, 0.f, 0.f};
    if (BIASMODE == 2) {
      float4 t4 = *(const float4*)&biasp[row];
      br[0] = t4.x; br[1] = t4.y; br[2] = t4.z; br[3] = t4.w;
    }
#pragma unroll
    for (int n = 0; n < 4; ++n) {
      const int col = brow0 + wc * 64 + n * 16 + lo;
#pragma unroll
      for (int j = 0; j < 4; ++j)
        store_out(&C[(long long)(row + j) * ldc + col],
                  acc[m][n][j] * scale + bcol[n] + br[j]);
    }
  }
}

// ---------------------------------------------------------------------------
__global__ void cvt_f32_bf16(const float* __restrict__ in, bf16* __restrict__ out,
                             long long n4) {
  long long i = (long long)blockIdx.x * 256 + threadIdx.x;
  if (i >= n4) return;
  float4 v = reinterpret_cast<const float4*>(in)[i];
  union { bf16 h[4]; unsigned long long u; } cv;
  cv.h[0] = __float2bfloat16(v.x);
  cv.h[1] = __float2bfloat16(v.y);
  cv.h[2] = __float2bfloat16(v.z);
  cv.h[3] = __float2bfloat16(v.w);
  reinterpret_cast<unsigned long long*>(out)[i] = cv.u;
}

// four 1024x1024 f32 -> bf16 transposes in one launch (blockIdx.z selects)
__global__ void transpose4_f32_to_bf16(const float* __restrict__ W0, const float* __restrict__ W1,
                                       const float* __restrict__ W2, const float* __restrict__ W3,
                                       bf16* __restrict__ O0, bf16* __restrict__ O1,
                                       bf16* __restrict__ O2, bf16* __restrict__ O3) {
  const float* in; bf16* out;
  switch (blockIdx.z) {
    case 0: in = W0; out = O0; break;
    case 1: in = W1; out = O1; break;
    case 2: in = W2; out = O2; break;
    default: in = W3; out = O3; break;
  }
  __shared__ float tile[32][33];
  const int bx = blockIdx.x * 32, by = blockIdx.y * 32;
  const int tx = threadIdx.x & 31, ty = threadIdx.x >> 5;
#pragma unroll
  for (int i = 0; i < 32; i += 8)
    tile[ty + i][tx] = in[(long long)(by + ty + i) * 1024 + bx + tx];
  __syncthreads();
#pragma unroll
  for (int i = 0; i < 32; i += 8)
    out[(long long)(bx + ty + i) * 1024 + by + tx] = __float2bfloat16(tile[tx][ty + i]);
}

// ---------------------------------------------------------------------------
// masked softmax over rows of S (bf16, already scaled), IN-PLACE. one block/row.
__global__ void softmax_mask(bf16* __restrict__ S, const int* __restrict__ mask) {
  const int row = blockIdx.x;  // b*1024 + q
  const int b = row >> 10;
  bf16* s = S + (long long)row * 2048;
  const int* mk = mask + b * 2048;
  const int t = threadIdx.x;
  const int lane = t & 63, wid = t >> 6;

  s16x8 xv = reinterpret_cast<const s16x8*>(s)[t];
  int4 m0 = reinterpret_cast<const int4*>(mk)[t * 2];
  int4 m1 = reinterpret_cast<const int4*>(mk)[t * 2 + 1];

  union { s16x8 v; bf16 h[8]; } u;
  u.v = xv;
  float v[8];
  const int mm[8] = {m0.x, m0.y, m0.z, m0.w, m1.x, m1.y, m1.z, m1.w};
#pragma unroll
  for (int j = 0; j < 8; ++j) v[j] = mm[j] ? __bfloat162float(u.h[j]) : -INFINITY;

  float mx = v[0];
#pragma unroll
  for (int j = 1; j < 8; ++j) mx = fmaxf(mx, v[j]);
  for (int off = 32; off; off >>= 1) mx = fmaxf(mx, __shfl_xor(mx, off, 64));
  __shared__ float redm[4];
  if (lane == 0) redm[wid] = mx;
  __syncthreads();
  mx = fmaxf(fmaxf(redm[0], redm[1]), fmaxf(redm[2], redm[3]));

  float e[8], sum = 0.f;
#pragma unroll
  for (int j = 0; j < 8; ++j) { e[j] = __expf(v[j] - mx); sum += e[j]; }
  for (int off = 32; off; off >>= 1) sum += __shfl_xor(sum, off, 64);
  __shared__ float reds[4];
  if (lane == 0) reds[wid] = sum;
  __syncthreads();
  sum = reds[0] + reds[1] + reds[2] + reds[3];
  const float inv = 1.0f / sum;

  union { bf16 h[8]; s16x8 v; } o;
#pragma unroll
  for (int j = 0; j < 8; ++j) o.h[j] = __float2bfloat16(e[j] * inv);
  reinterpret_cast<s16x8*>(s)[t] = o.v;
}

// ---------------------------------------------------------------------------
extern "C" void kernel_launch(void* const* d_in, const int* in_sizes, int n_in,
                              void* d_out, int out_size, void* d_ws, size_t ws_size,
                              hipStream_t stream) {
  const float* query = (const float*)d_in[0];      // [8,1024,1024]
  const float* key_value = (const float*)d_in[1];  // [8,2048,1024]
  const int* key_mask = (const int*)d_in[2];       // [8,2048]
  const float* Wq = (const float*)d_in[3];
  const float* bq = (const float*)d_in[4];
  const float* Wk = (const float*)d_in[5];
  const float* bk = (const float*)d_in[6];
  const float* Wv = (const float*)d_in[7];
  const float* bv = (const float*)d_in[8];
  const float* Wo = (const float*)d_in[9];
  const float* bo = (const float*)d_in[10];
  float* out = (float*)d_out;

  char* ws = (char*)d_ws;
  size_t off = 0;
  auto alloc = [&](size_t bytes) {
    char* p = ws + off;
    off += (bytes + 255) & ~(size_t)255;
    return p;
  };
  bf16* qb  = (bf16*)alloc(8192ull * 1024 * 2);     // query bf16
  bf16* kvb = (bf16*)alloc(16384ull * 1024 * 2);    // key_value bf16
  bf16* WqT = (bf16*)alloc(1024ull * 1024 * 2);
  bf16* WkT = (bf16*)alloc(1024ull * 1024 * 2);
  bf16* WvT = (bf16*)alloc(1024ull * 1024 * 2);
  bf16* WoT = (bf16*)alloc(1024ull * 1024 * 2);
  bf16* Qb  = (bf16*)alloc(8192ull * 1024 * 2);     // later: Cb
  bf16* Kb  = (bf16*)alloc(16384ull * 1024 * 2);    // K proj [8][2048][1024]
  bf16* VT  = (bf16*)alloc(8192ull * 2048 * 2);     // V^T [8][1024][2048]
  bf16* S   = (bf16*)alloc(8ull * 1024 * 2048 * 2); // scores, softmax in-place
  bf16* Cb = Qb;  // alias: Qb dead after scores GEMM

  // 1. conversions / weight prep (one batched transpose launch)
  cvt_f32_bf16<<<8192, 256, 0, stream>>>(query, qb, 8192ll * 1024 / 4);
  cvt_f32_bf16<<<16384, 256, 0, stream>>>(key_value, kvb, 16384ll * 1024 / 4);
  transpose4_f32_to_bf16<<<dim3(32, 32, 4), 256, 0, stream>>>(
      Wq, Wk, Wv, Wo, WqT, WkT, WvT, WoT);

  // 2. Q projection: [8192,1024] @ Wq + bq -> Qb
  gemm_bt<bf16, 1, 2><<<512, 256, 0, stream>>>(
      qb, WqT, Qb, bq, 1.f, 1024, 1024, 1024, 1024, 8, 0, 0, 0);

  // 3. K projection: [16384,1024] @ Wk + bk -> Kb
  gemm_bt<bf16, 1, 2><<<1024, 256, 0, stream>>>(
      kvb, WkT, Kb, bk, 1.f, 1024, 1024, 1024, 1024, 8, 0, 0, 0);

  // 4. V^T projection (direct): VT[b][h][s] = sum_d WvT[h][d]*kv[b][s][d] + bv[h]
  gemm_bt<bf16, 2, 1><<<1024, 256, 0, stream>>>(
      WvT, kvb, VT, bv, 1.f, 1024, 1024, 1024, 2048, 16,
      0, 2048ll * 1024, 1024ll * 2048);

  // 5. scores: S = (Q @ K^T)/32, bf16, batch->XCD pinned
  gemm_bt<bf16, 0, 1><<<1024, 256, 0, stream>>>(
      Qb, Kb, S, nullptr, 0.03125f, 1024, 1024, 1024, 2048, 16,
      1024ll * 1024, 2048ll * 1024, 1024ll * 2048);

  // 6. masked softmax in-place -> P
  softmax_mask<<<8192, 256, 0, stream>>>(S, key_mask);

  // 7. context = P @ V (BT = VT[h][s]), batch->XCD pinned
  gemm_bt<bf16, 0, 1><<<512, 256, 0, stream>>>(
      S, VT, Cb, nullptr, 1.f, 2048, 2048, 2048, 1024, 8,
      1024ll * 2048, 1024ll * 2048, 1024ll * 1024);

  // 8. out = Cb @ Wo + bo (f32)
  gemm_bt<float, 1, 2><<<512, 256, 0, stream>>>(
      Cb, WoT, out, bo, 1.f, 1024, 1024, 1024, 1024, 8, 0, 0, 0);
}

// Round 7
// 286.589 us; speedup vs baseline: 1.0835x; 1.0835x over previous
//
#include <hip/hip_runtime.h>
#include <hip/hip_bf16.h>

typedef __hip_bfloat16 bf16;
typedef float f32x4 __attribute__((ext_vector_type(4)));
typedef short s16x8 __attribute__((ext_vector_type(8)));

// ---------------------------------------------------------------------------
__device__ __forceinline__ void async_load16(const void* g, void* lds) {
  __builtin_amdgcn_global_load_lds(
      (const __attribute__((address_space(1))) void*)g,
      (__attribute__((address_space(3))) void*)lds, 16, 0, 0);
}

#define WAITV(N) asm volatile("s_waitcnt vmcnt(" #N ")" ::: "memory")

__device__ __forceinline__ void wg_barrier() {
  asm volatile("" ::: "memory");
  __builtin_amdgcn_s_barrier();
  asm volatile("" ::: "memory");
}

__device__ __forceinline__ f32x4 MFMA(s16x8 a, s16x8 b, f32x4 c) {
  return __builtin_amdgcn_mfma_f32_16x16x32_bf16(a, b, c, 0, 0, 0);
}

__device__ __forceinline__ void store_out(float* p, float v) { *p = v; }
__device__ __forceinline__ void store_out(bf16* p, float v) { *p = __float2bfloat16(v); }

// ---------------------------------------------------------------------------
// 256x256 tile, BK=64, 8 waves (2M x 4N), 4 phases/K-tile. NO sched_barrier
// (m141: order-pinning poison). Pre-barrier ds_reads+stage, counted WAITV,
// setprio around MFMA clusters. Swizzled LDS (both sides, rule 21); r4
// verified: conflicts = 0, absmax exact.
// vmcnt ledger (2 loads/stage; verified r4):
//   prologue: A0(0) B0(0) A1(0) B1(0) A0(1) B0(1) -> WAITV(8)  [A0/B0(0) in]
//   ph0: +A1(t+1)  ph1: +B1(t+1) -> WAITV(8)  [A1/B1(t) in]   (tail: 0)
//   ph2: +A0(t+2)  ph3: +B0(t+2) -> WAITV(8)  [A0/B0(t+1) in] (tail: 4/skip)
// Overwrite safety (verified): each stage's target region's last readers
// completed >=1 shared barrier before the stage issues.
template <typename OutT, int BIASMODE, int SWZ>
__global__ __launch_bounds__(512, 2)
void gemm256(const bf16* __restrict__ Ag, const bf16* __restrict__ Bg,
             OutT* Cg, const float* __restrict__ biasp, float scale,
             int K, int lda, int ldb, int ldc, int ntx,
             long long sA, long long sB, long long sC) {
  __shared__ bf16 As[2][2][256 * 32];
  __shared__ bf16 Bs[2][2][256 * 32];

  const int id = blockIdx.x;
  int bz = 0, tile;
  if (SWZ == 1) { bz = id & 7; tile = id >> 3; }
  else { const int q = gridDim.x >> 3; tile = (id & 7) * q + (id >> 3); }
  const int tn = tile % ntx, tm = tile / ntx;

  const bf16* A = Ag + bz * sA + (long long)tm * 256 * lda;
  const bf16* BT = Bg + bz * sB + (long long)tn * 256 * ldb;
  OutT* C = Cg + bz * sC;

  const int t = threadIdx.x;
  const int lane = t & 63, wid = t >> 6;
  const int wr = wid >> 2, wc = wid & 3;          // 2 (M) x 4 (N)
  const int lo = lane & 15, hi = lane >> 4;
  const int loff = (hi ^ ((lo >> 1) & 3)) * 8;    // swizzled read slot

  const int NT = K >> 6;

  // staging: chunk q=(t+j*512): row q>>2, phys slot q&3, global slot XOR'd
  int srow[2], sgo[2];
#pragma unroll
  for (int j = 0; j < 2; ++j) {
    const int q = t + j * 512;
    const int row = q >> 2;
    srow[j] = row;
    sgo[j] = ((q & 3) ^ ((row >> 1) & 3)) * 8;
  }

  auto stageA = [&](const bf16* gp, bf16* region) {
#pragma unroll
    for (int j = 0; j < 2; ++j)
      async_load16(gp + (long long)srow[j] * lda + sgo[j], region + (t + j * 512) * 8);
  };
  auto stageB = [&](const bf16* gp, bf16* region) {
#pragma unroll
    for (int j = 0; j < 2; ++j)
      async_load16(gp + (long long)srow[j] * ldb + sgo[j], region + (t + j * 512) * 8);
  };

  f32x4 acc[8][4] = {};

  // ---- prologue
  stageA(A, &As[0][0][0]);
  stageB(BT, &Bs[0][0][0]);
  stageA(A + 32, &As[0][1][0]);
  stageB(BT + 32, &Bs[0][1][0]);
  stageA(A + 64, &As[1][0][0]);
  stageB(BT + 64, &Bs[1][0][0]);
  WAITV(8);
  wg_barrier();

  const int abase = wr * 128 + lo;
  const int bbase = wc * 64 + lo;

  for (int kt = 0; kt < NT; ++kt) {
    const int c = kt & 1;
    const bf16* A0r = &As[c][0][0];
    const bf16* A1r = &As[c][1][0];
    const bf16* B0r = &Bs[c][0][0];
    const bf16* B1r = &Bs[c][1][0];
    s16x8 a[8], b0, b1;

    // ---- ph0: kh0 x n{0,1}
    if (kt + 1 < NT) stageA(A + (kt + 1) * 64 + 32, &As[c ^ 1][1][0]);
#pragma unroll
    for (int m = 0; m < 8; ++m)
      a[m] = *(const s16x8*)&A0r[(abase + m * 16) * 32 + loff];
    b0 = *(const s16x8*)&B0r[bbase * 32 + loff];
    b1 = *(const s16x8*)&B0r[(bbase + 16) * 32 + loff];
    wg_barrier();
    __builtin_amdgcn_s_setprio(1);
#pragma unroll
    for (int m = 0; m < 8; ++m) {
      acc[m][0] = MFMA(a[m], b0, acc[m][0]);
      acc[m][1] = MFMA(a[m], b1, acc[m][1]);
    }
    __builtin_amdgcn_s_setprio(0);
    wg_barrier();

    // ---- ph1: kh0 x n{2,3} (reuse a[])
    if (kt + 1 < NT) stageB(BT + (kt + 1) * 64 + 32, &Bs[c ^ 1][1][0]);
    b0 = *(const s16x8*)&B0r[(bbase + 32) * 32 + loff];
    b1 = *(const s16x8*)&B0r[(bbase + 48) * 32 + loff];
    wg_barrier();
    __builtin_amdgcn_s_setprio(1);
#pragma unroll
    for (int m = 0; m < 8; ++m) {
      acc[m][2] = MFMA(a[m], b0, acc[m][2]);
      acc[m][3] = MFMA(a[m], b1, acc[m][3]);
    }
    __builtin_amdgcn_s_setprio(0);
    if (kt + 1 < NT) { WAITV(8); } else { WAITV(0); }
    wg_barrier();

    // ---- ph2: kh1 x n{0,1}
    if (kt + 2 < NT) stageA(A + (kt + 2) * 64, &As[c][0][0]);
#pragma unroll
    for (int m = 0; m < 8; ++m)
      a[m] = *(const s16x8*)&A1r[(abase + m * 16) * 32 + loff];
    b0 = *(const s16x8*)&B1r[bbase * 32 + loff];
    b1 = *(const s16x8*)&B1r[(bbase + 16) * 32 + loff];
    wg_barrier();
    __builtin_amdgcn_s_setprio(1);
#pragma unroll
    for (int m = 0; m < 8; ++m) {
      acc[m][0] = MFMA(a[m], b0, acc[m][0]);
      acc[m][1] = MFMA(a[m], b1, acc[m][1]);
    }
    __builtin_amdgcn_s_setprio(0);
    wg_barrier();

    // ---- ph3: kh1 x n{2,3}
    if (kt + 2 < NT) stageB(BT + (kt + 2) * 64, &Bs[c][0][0]);
    b0 = *(const s16x8*)&B1r[(bbase + 32) * 32 + loff];
    b1 = *(const s16x8*)&B1r[(bbase + 48) * 32 + loff];
    wg_barrier();
    __builtin_amdgcn_s_setprio(1);
#pragma unroll
    for (int m = 0; m < 8; ++m) {
      acc[m][2] = MFMA(a[m], b0, acc[m][2]);
      acc[m][3] = MFMA(a[m], b1, acc[m][3]);
    }
    __builtin_amdgcn_s_setprio(0);
    if (kt + 2 < NT) { WAITV(8); }
    else if (kt + 1 < NT) { WAITV(4); }
    wg_barrier();
  }

  // ---- epilogue: col = lane&15, row = (lane>>4)*4 + reg
  float bcol[4] = {0.f, 0.f, 0.f, 0.f};
  if (BIASMODE == 1) {
#pragma unroll
    for (int n = 0; n < 4; ++n)
      bcol[n] = biasp[tn * 256 + wc * 64 + n * 16 + lo];
  }
#pragma unroll
  for (int m = 0; m < 8; ++m) {
    const int row = tm * 256 + wr * 128 + m * 16 + hi * 4;
    float br[4] = {0.f, 0.f, 0.f, 0.f};
    if (BIASMODE == 2) {
      float4 t4 = *(const float4*)&biasp[row];
      br[0] = t4.x; br[1] = t4.y; br[2] = t4.z; br[3] = t4.w;
    }
#pragma unroll
    for (int n = 0; n < 4; ++n) {
      const int col = tn * 256 + wc * 64 + n * 16 + lo;
#pragma unroll
      for (int j = 0; j < 4; ++j)
        store_out(&C[(long long)(row + j) * ldc + col],
                  acc[m][n][j] * scale + bcol[n] + br[j]);
    }
  }
}

// ---------------------------------------------------------------------------
// r5-proven 2-phase 128x128 GEMM (for Q/PV/O projections).
template <typename OutT, int BIASMODE, int SWZ>
__global__ void gemm_bt(const bf16* __restrict__ Ag, const bf16* __restrict__ Bg,
                        OutT* Cg, const float* __restrict__ biasp, float scale,
                        int K, int lda, int ldb, int ldc, int ntx,
                        long long sA, long long sB, long long sC) {
  __shared__ bf16 As[2][128 * 32];
  __shared__ bf16 Bs[2][128 * 32];

  const int id = blockIdx.x;
  int bz = 0, tile;
  if (SWZ == 1) { bz = id & 7; tile = id >> 3; }
  else { const int q = gridDim.x >> 3; tile = (id & 7) * q + (id >> 3); }
  const int tn = tile % ntx, tm = tile / ntx;

  const bf16* A = Ag + bz * sA;
  const bf16* BT = Bg + bz * sB;
  OutT* C = Cg + bz * sC;

  const int t = threadIdx.x;
  const int lane = t & 63;
  const int wid = t >> 6;
  const int wr = wid >> 1, wc = wid & 1;
  const int lo = lane & 15, hi = lane >> 4;

  const int arow0 = tm * 128, brow0 = tn * 128;

  const int idx0 = t, idx1 = 256 + t;
  const int r0 = idx0 >> 2, c0 = (idx0 & 3) * 8;
  const int r1 = idx1 >> 2, c1 = (idx1 & 3) * 8;
  const bf16* a0 = A + (long long)(arow0 + r0) * lda + c0;
  const bf16* a1 = A + (long long)(arow0 + r1) * lda + c1;
  const bf16* b0 = BT + (long long)(brow0 + r0) * ldb + c0;
  const bf16* b1 = BT + (long long)(brow0 + r1) * ldb + c1;

  f32x4 acc[4][4] = {};
  const int nt = K >> 5;

  async_load16(a0, &As[0][idx0 * 8]);
  async_load16(a1, &As[0][idx1 * 8]);
  async_load16(b0, &Bs[0][idx0 * 8]);
  async_load16(b1, &Bs[0][idx1 * 8]);
  __syncthreads();

  int cur = 0;
  for (int kt = 0; kt < nt; ++kt) {
    const int nxt = cur ^ 1;
    if (kt + 1 < nt) {
      const int k0 = (kt + 1) << 5;
      async_load16(a0 + k0, &As[nxt][idx0 * 8]);
      async_load16(a1 + k0, &As[nxt][idx1 * 8]);
      async_load16(b0 + k0, &Bs[nxt][idx0 * 8]);
      async_load16(b1 + k0, &Bs[nxt][idx1 * 8]);
    }
    s16x8 a[4], b[4];
#pragma unroll
    for (int m = 0; m < 4; ++m)
      a[m] = *(const s16x8*)&As[cur][(wr * 64 + m * 16 + lo) * 32 + hi * 8];
#pragma unroll
    for (int n = 0; n < 4; ++n)
      b[n] = *(const s16x8*)&Bs[cur][(wc * 64 + n * 16 + lo) * 32 + hi * 8];
#pragma unroll
    for (int m = 0; m < 4; ++m)
#pragma unroll
      for (int n = 0; n < 4; ++n)
        acc[m][n] = __builtin_amdgcn_mfma_f32_16x16x32_bf16(a[m], b[n], acc[m][n], 0, 0, 0);
    __syncthreads();
    cur = nxt;
  }

  float bcol[4] = {0.f, 0.f, 0.f, 0.f};
  if (BIASMODE == 1) {
#pragma unroll
    for (int n = 0; n < 4; ++n)
      bcol[n] = biasp[brow0 + wc * 64 + n * 16 + lo];
  }
#pragma unroll
  for (int m = 0; m < 4; ++m) {
    const int row = arow0 + wr * 64 + m * 16 + hi * 4;
    float br[4] = {0.f, 0.f, 0.f, 0.f};
    if (BIASMODE == 2) {
      float4 t4 = *(const float4*)&biasp[row];
      br[0] = t4.x; br[1] = t4.y; br[2] = t4.z; br[3] = t4.w;
    }
#pragma unroll
    for (int n = 0; n < 4; ++n) {
      const int col = brow0 + wc * 64 + n * 16 + lo;
#pragma unroll
      for (int j = 0; j < 4; ++j)
        store_out(&C[(long long)(row + j) * ldc + col],
                  acc[m][n][j] * scale + bcol[n] + br[j]);
    }
  }
}

// ---------------------------------------------------------------------------
__global__ void cvt_f32_bf16(const float* __restrict__ in, bf16* __restrict__ out,
                             long long n4) {
  long long i = (long long)blockIdx.x * 256 + threadIdx.x;
  if (i >= n4) return;
  float4 v = reinterpret_cast<const float4*>(in)[i];
  union { bf16 h[4]; unsigned long long u; } cv;
  cv.h[0] = __float2bfloat16(v.x);
  cv.h[1] = __float2bfloat16(v.y);
  cv.h[2] = __float2bfloat16(v.z);
  cv.h[3] = __float2bfloat16(v.w);
  reinterpret_cast<unsigned long long*>(out)[i] = cv.u;
}

__global__ void transpose4_f32_to_bf16(const float* __restrict__ W0, const float* __restrict__ W1,
                                       const float* __restrict__ W2, const float* __restrict__ W3,
                                       bf16* __restrict__ O0, bf16* __restrict__ O1,
                                       bf16* __restrict__ O2, bf16* __restrict__ O3) {
  const float* in; bf16* out;
  switch (blockIdx.z) {
    case 0: in = W0; out = O0; break;
    case 1: in = W1; out = O1; break;
    case 2: in = W2; out = O2; break;
    default: in = W3; out = O3; break;
  }
  __shared__ float tile[32][33];
  const int bx = blockIdx.x * 32, by = blockIdx.y * 32;
  const int tx = threadIdx.x & 31, ty = threadIdx.x >> 5;
#pragma unroll
  for (int i = 0; i < 32; i += 8)
    tile[ty + i][tx] = in[(long long)(by + ty + i) * 1024 + bx + tx];
  __syncthreads();
#pragma unroll
  for (int i = 0; i < 32; i += 8)
    out[(long long)(bx + ty + i) * 1024 + by + tx] = __float2bfloat16(tile[tx][ty + i]);
}

// ---------------------------------------------------------------------------
__global__ void softmax_mask(bf16* __restrict__ S, const int* __restrict__ mask) {
  const int row = blockIdx.x;
  const int b = row >> 10;
  bf16* s = S + (long long)row * 2048;
  const int* mk = mask + b * 2048;
  const int t = threadIdx.x;
  const int lane = t & 63, wid = t >> 6;

  s16x8 xv = reinterpret_cast<const s16x8*>(s)[t];
  int4 m0 = reinterpret_cast<const int4*>(mk)[t * 2];
  int4 m1 = reinterpret_cast<const int4*>(mk)[t * 2 + 1];

  union { s16x8 v; bf16 h[8]; } u;
  u.v = xv;
  float v[8];
  const int mm[8] = {m0.x, m0.y, m0.z, m0.w, m1.x, m1.y, m1.z, m1.w};
#pragma unroll
  for (int j = 0; j < 8; ++j) v[j] = mm[j] ? __bfloat162float(u.h[j]) : -INFINITY;

  float mx = v[0];
#pragma unroll
  for (int j = 1; j < 8; ++j) mx = fmaxf(mx, v[j]);
  for (int off = 32; off; off >>= 1) mx = fmaxf(mx, __shfl_xor(mx, off, 64));
  __shared__ float redm[4];
  if (lane == 0) redm[wid] = mx;
  __syncthreads();
  mx = fmaxf(fmaxf(redm[0], redm[1]), fmaxf(redm[2], redm[3]));

  float e[8], sum = 0.f;
#pragma unroll
  for (int j = 0; j < 8; ++j) { e[j] = __expf(v[j] - mx); sum += e[j]; }
  for (int off = 32; off; off >>= 1) sum += __shfl_xor(sum, off, 64);
  __shared__ float reds[4];
  if (lane == 0) reds[wid] = sum;
  __syncthreads();
  sum = reds[0] + reds[1] + reds[2] + reds[3];
  const float inv = 1.0f / sum;

  union { bf16 h[8]; s16x8 v; } o;
#pragma unroll
  for (int j = 0; j < 8; ++j) o.h[j] = __float2bfloat16(e[j] * inv);
  reinterpret_cast<s16x8*>(s)[t] = o.v;
}

// ---------------------------------------------------------------------------
extern "C" void kernel_launch(void* const* d_in, const int* in_sizes, int n_in,
                              void* d_out, int out_size, void* d_ws, size_t ws_size,
                              hipStream_t stream) {
  const float* query = (const float*)d_in[0];      // [8,1024,1024]
  const float* key_value = (const float*)d_in[1];  // [8,2048,1024]
  const int* key_mask = (const int*)d_in[2];       // [8,2048]
  const float* Wq = (const float*)d_in[3];
  const float* bq = (const float*)d_in[4];
  const float* Wk = (const float*)d_in[5];
  const float* bk = (const float*)d_in[6];
  const float* Wv = (const float*)d_in[7];
  const float* bv = (const float*)d_in[8];
  const float* Wo = (const float*)d_in[9];
  const float* bo = (const float*)d_in[10];
  float* out = (float*)d_out;

  char* ws = (char*)d_ws;
  size_t off = 0;
  auto alloc = [&](size_t bytes) {
    char* p = ws + off;
    off += (bytes + 255) & ~(size_t)255;
    return p;
  };
  bf16* qb  = (bf16*)alloc(8192ull * 1024 * 2);
  bf16* kvb = (bf16*)alloc(16384ull * 1024 * 2);
  bf16* WqT = (bf16*)alloc(1024ull * 1024 * 2);
  bf16* WkT = (bf16*)alloc(1024ull * 1024 * 2);
  bf16* WvT = (bf16*)alloc(1024ull * 1024 * 2);
  bf16* WoT = (bf16*)alloc(1024ull * 1024 * 2);
  bf16* Qb  = (bf16*)alloc(8192ull * 1024 * 2);
  bf16* Kb  = (bf16*)alloc(16384ull * 1024 * 2);
  bf16* VT  = (bf16*)alloc(8192ull * 2048 * 2);
  bf16* S   = (bf16*)alloc(8ull * 1024 * 2048 * 2);
  bf16* Cb = Qb;  // alias: Qb dead after scores GEMM

  // 1. conversions / weight prep
  cvt_f32_bf16<<<8192, 256, 0, stream>>>(query, qb, 8192ll * 1024 / 4);
  cvt_f32_bf16<<<16384, 256, 0, stream>>>(key_value, kvb, 16384ll * 1024 / 4);
  transpose4_f32_to_bf16<<<dim3(32, 32, 4), 256, 0, stream>>>(
      Wq, Wk, Wv, Wo, WqT, WkT, WvT, WoT);

  // 2. Q projection (2-phase 128^2): [8192,1024] @ Wq + bq -> Qb
  gemm_bt<bf16, 1, 2><<<512, 256, 0, stream>>>(
      qb, WqT, Qb, bq, 1.f, 1024, 1024, 1024, 1024, 8, 0, 0, 0);

  // 3. K projection (8-phase 256^2): [16384,1024] @ Wk + bk -> Kb
  gemm256<bf16, 1, 2><<<256, 512, 0, stream>>>(
      kvb, WkT, Kb, bk, 1.f, 1024, 1024, 1024, 1024, 4, 0, 0, 0);

  // 4. V^T projection (8-phase 256^2, row bias):
  //    VT[b][h][s] = sum_d WvT[h][d]*kv[b][s][d] + bv[h]
  gemm256<bf16, 2, 1><<<256, 512, 0, stream>>>(
      WvT, kvb, VT, bv, 1.f, 1024, 1024, 1024, 2048, 8,
      0, 2048ll * 1024, 1024ll * 2048);

  // 5. scores (8-phase 256^2): S = (Q @ K^T)/32, batch->XCD pinned
  gemm256<bf16, 0, 1><<<256, 512, 0, stream>>>(
      Qb, Kb, S, nullptr, 0.03125f, 1024, 1024, 1024, 2048, 8,
      1024ll * 1024, 2048ll * 1024, 1024ll * 2048);

  // 6. masked softmax in-place -> P
  softmax_mask<<<8192, 256, 0, stream>>>(S, key_mask);

  // 7. context = P @ V (2-phase 128^2), batch->XCD pinned
  gemm_bt<bf16, 0, 1><<<512, 256, 0, stream>>>(
      S, VT, Cb, nullptr, 1.f, 2048, 2048, 2048, 1024, 8,
      1024ll * 2048, 1024ll * 2048, 1024ll * 1024);

  // 8. out = Cb @ Wo + bo (2-phase 128^2, f32)
  gemm_bt<float, 1, 2><<<512, 256, 0, stream>>>(
      Cb, WoT, out, bo, 1.f, 1024, 1024, 1024, 1024, 8, 0, 0, 0);
}

// Round 8
// 285.356 us; speedup vs baseline: 1.0882x; 1.0043x over previous
//
#include <hip/hip_runtime.h>
#include <hip/hip_bf16.h>

typedef __hip_bfloat16 bf16;
typedef float f32x4 __attribute__((ext_vector_type(4)));
typedef short s16x8 __attribute__((ext_vector_type(8)));

// ---------------------------------------------------------------------------
__device__ __forceinline__ void async_load16(const void* g, void* lds) {
  __builtin_amdgcn_global_load_lds(
      (const __attribute__((address_space(1))) void*)g,
      (__attribute__((address_space(3))) void*)lds, 16, 0, 0);
}

__device__ __forceinline__ void store_out(float* p, float v) { *p = v; }
__device__ __forceinline__ void store_out(bf16* p, float v) { *p = __float2bfloat16(v); }

// ---------------------------------------------------------------------------
// C[M,N] = scale*(A[M,K] @ BT[N,K]^T) + bias. bf16 in, f32 acc.
// 128xBN tile (BN=128 or 64), BK=32, 4 waves, 2-phase double-buffered LDS
// with next-tile prefetch. r5-proven loop structure; BN=64 variant raises
// blocks/CU for small grids (24KB LDS -> up to 6 blocks/CU).
// BIASMODE: 0 none, 1 per-column, 2 per-row.
// SWZ=1: batched, id&7 = batch (XCD pin). SWZ=2: chunked XCD swizzle.
template <typename OutT, int BIASMODE, int SWZ, int BN>
__global__ void gemm_bt(const bf16* __restrict__ Ag, const bf16* __restrict__ Bg,
                        OutT* Cg, const float* __restrict__ biasp, float scale,
                        int K, int lda, int ldb, int ldc, int ntx,
                        long long sA, long long sB, long long sC) {
  constexpr int NFR = BN / 32;      // n-frags per wave (waves 2x2; wave N = BN/2)
  constexpr int BCH = BN / 64;      // B staging chunks per thread (2 or 1)
  __shared__ bf16 As[2][128 * 32];
  __shared__ bf16 Bs[2][BN * 32];

  const int id = blockIdx.x;
  int bz = 0, tile;
  if (SWZ == 1) { bz = id & 7; tile = id >> 3; }
  else { const int q = gridDim.x >> 3; tile = (id & 7) * q + (id >> 3); }
  const int tn = tile % ntx, tm = tile / ntx;

  const bf16* A = Ag + bz * sA;
  const bf16* BT = Bg + bz * sB;
  OutT* C = Cg + bz * sC;

  const int t = threadIdx.x;
  const int lane = t & 63;
  const int wid = t >> 6;
  const int wr = wid >> 1, wc = wid & 1;
  const int lo = lane & 15, hi = lane >> 4;

  const int arow0 = tm * 128, brow0 = tn * BN;

  // staging: A = 2 chunks/thread; B = BCH chunks/thread (16B each, row=64B)
  const int idx0 = t, idx1 = 256 + t;
  const int r0 = idx0 >> 2, c0 = (idx0 & 3) * 8;
  const int r1 = idx1 >> 2, c1 = (idx1 & 3) * 8;
  const bf16* a0 = A + (long long)(arow0 + r0) * lda + c0;
  const bf16* a1 = A + (long long)(arow0 + r1) * lda + c1;
  const bf16* b0 = BT + (long long)(brow0 + r0) * ldb + c0;
  const bf16* b1 = BT + (long long)(brow0 + r1) * ldb + c1;

  f32x4 acc[4][NFR] = {};
  const int nt = K >> 5;

  // prologue: stage tile 0
  async_load16(a0, &As[0][idx0 * 8]);
  async_load16(a1, &As[0][idx1 * 8]);
  async_load16(b0, &Bs[0][idx0 * 8]);
  if (BCH == 2) async_load16(b1, &Bs[0][idx1 * 8]);
  __syncthreads();

  int cur = 0;
  for (int kt = 0; kt < nt; ++kt) {
    const int nxt = cur ^ 1;
    if (kt + 1 < nt) {  // issue next tile's loads BEFORE computing current
      const int k0 = (kt + 1) << 5;
      async_load16(a0 + k0, &As[nxt][idx0 * 8]);
      async_load16(a1 + k0, &As[nxt][idx1 * 8]);
      async_load16(b0 + k0, &Bs[nxt][idx0 * 8]);
      if (BCH == 2) async_load16(b1 + k0, &Bs[nxt][idx1 * 8]);
    }
    s16x8 a[4], b[NFR];
#pragma unroll
    for (int m = 0; m < 4; ++m)
      a[m] = *(const s16x8*)&As[cur][(wr * 64 + m * 16 + lo) * 32 + hi * 8];
#pragma unroll
    for (int n = 0; n < NFR; ++n)
      b[n] = *(const s16x8*)&Bs[cur][(wc * (BN / 2) + n * 16 + lo) * 32 + hi * 8];
#pragma unroll
    for (int m = 0; m < 4; ++m)
#pragma unroll
      for (int n = 0; n < NFR; ++n)
        acc[m][n] = __builtin_amdgcn_mfma_f32_16x16x32_bf16(a[m], b[n], acc[m][n], 0, 0, 0);
    __syncthreads();
    cur = nxt;
  }

  // C/D layout: col = lane&15, row = (lane>>4)*4 + reg
  float bcol[NFR];
#pragma unroll
  for (int n = 0; n < NFR; ++n) bcol[n] = 0.f;
  if (BIASMODE == 1) {
#pragma unroll
    for (int n = 0; n < NFR; ++n)
      bcol[n] = biasp[brow0 + wc * (BN / 2) + n * 16 + lo];
  }
#pragma unroll
  for (int m = 0; m < 4; ++m) {
    const int row = arow0 + wr * 64 + m * 16 + hi * 4;
    float br[4] = {0.f, 0.f, 0.f, 0.f};
    if (BIASMODE == 2) {
      float4 t4 = *(const float4*)&biasp[row];
      br[0] = t4.x; br[1] = t4.y; br[2] = t4.z; br[3] = t4.w;
    }
#pragma unroll
    for (int n = 0; n < NFR; ++n) {
      const int col = brow0 + wc * (BN / 2) + n * 16 + lo;
#pragma unroll
      for (int j = 0; j < 4; ++j)
        store_out(&C[(long long)(row + j) * ldc + col],
                  acc[m][n][j] * scale + bcol[n] + br[j]);
    }
  }
}

// ---------------------------------------------------------------------------
// merged f32->bf16 conversion for two arrays in one launch (fewer dispatch gaps)
__global__ void cvt2_f32_bf16(const float* __restrict__ inA, bf16* __restrict__ outA,
                              long long na4,
                              const float* __restrict__ inB, bf16* __restrict__ outB,
                              long long nb4) {
  long long i = (long long)blockIdx.x * 256 + threadIdx.x;
  if (i >= na4 + nb4) return;
  const float* in; bf16* out; long long j;
  if (i < na4) { in = inA; out = outA; j = i; }
  else { in = inB; out = outB; j = i - na4; }
  float4 v = reinterpret_cast<const float4*>(in)[j];
  union { bf16 h[4]; unsigned long long u; } cv;
  cv.h[0] = __float2bfloat16(v.x);
  cv.h[1] = __float2bfloat16(v.y);
  cv.h[2] = __float2bfloat16(v.z);
  cv.h[3] = __float2bfloat16(v.w);
  reinterpret_cast<unsigned long long*>(out)[j] = cv.u;
}

// four 1024x1024 f32 -> bf16 transposes in one launch (blockIdx.z selects)
__global__ void transpose4_f32_to_bf16(const float* __restrict__ W0, const float* __restrict__ W1,
                                       const float* __restrict__ W2, const float* __restrict__ W3,
                                       bf16* __restrict__ O0, bf16* __restrict__ O1,
                                       bf16* __restrict__ O2, bf16* __restrict__ O3) {
  const float* in; bf16* out;
  switch (blockIdx.z) {
    case 0: in = W0; out = O0; break;
    case 1: in = W1; out = O1; break;
    case 2: in = W2; out = O2; break;
    default: in = W3; out = O3; break;
  }
  __shared__ float tile[32][33];
  const int bx = blockIdx.x * 32, by = blockIdx.y * 32;
  const int tx = threadIdx.x & 31, ty = threadIdx.x >> 5;
#pragma unroll
  for (int i = 0; i < 32; i += 8)
    tile[ty + i][tx] = in[(long long)(by + ty + i) * 1024 + bx + tx];
  __syncthreads();
#pragma unroll
  for (int i = 0; i < 32; i += 8)
    out[(long long)(bx + ty + i) * 1024 + by + tx] = __float2bfloat16(tile[tx][ty + i]);
}

// ---------------------------------------------------------------------------
// masked softmax over rows of S (bf16, already scaled), IN-PLACE. one block/row.
__global__ void softmax_mask(bf16* __restrict__ S, const int* __restrict__ mask) {
  const int row = blockIdx.x;  // b*1024 + q
  const int b = row >> 10;
  bf16* s = S + (long long)row * 2048;
  const int* mk = mask + b * 2048;
  const int t = threadIdx.x;
  const int lane = t & 63, wid = t >> 6;

  s16x8 xv = reinterpret_cast<const s16x8*>(s)[t];
  int4 m0 = reinterpret_cast<const int4*>(mk)[t * 2];
  int4 m1 = reinterpret_cast<const int4*>(mk)[t * 2 + 1];

  union { s16x8 v; bf16 h[8]; } u;
  u.v = xv;
  float v[8];
  const int mm[8] = {m0.x, m0.y, m0.z, m0.w, m1.x, m1.y, m1.z, m1.w};
#pragma unroll
  for (int j = 0; j < 8; ++j) v[j] = mm[j] ? __bfloat162float(u.h[j]) : -INFINITY;

  float mx = v[0];
#pragma unroll
  for (int j = 1; j < 8; ++j) mx = fmaxf(mx, v[j]);
  for (int off = 32; off; off >>= 1) mx = fmaxf(mx, __shfl_xor(mx, off, 64));
  __shared__ float redm[4];
  if (lane == 0) redm[wid] = mx;
  __syncthreads();
  mx = fmaxf(fmaxf(redm[0], redm[1]), fmaxf(redm[2], redm[3]));

  float e[8], sum = 0.f;
#pragma unroll
  for (int j = 0; j < 8; ++j) { e[j] = __expf(v[j] - mx); sum += e[j]; }
  for (int off = 32; off; off >>= 1) sum += __shfl_xor(sum, off, 64);
  __shared__ float reds[4];
  if (lane == 0) reds[wid] = sum;
  __syncthreads();
  sum = reds[0] + reds[1] + reds[2] + reds[3];
  const float inv = 1.0f / sum;

  union { bf16 h[8]; s16x8 v; } o;
#pragma unroll
  for (int j = 0; j < 8; ++j) o.h[j] = __float2bfloat16(e[j] * inv);
  reinterpret_cast<s16x8*>(s)[t] = o.v;
}

// ---------------------------------------------------------------------------
extern "C" void kernel_launch(void* const* d_in, const int* in_sizes, int n_in,
                              void* d_out, int out_size, void* d_ws, size_t ws_size,
                              hipStream_t stream) {
  const float* query = (const float*)d_in[0];      // [8,1024,1024]
  const float* key_value = (const float*)d_in[1];  // [8,2048,1024]
  const int* key_mask = (const int*)d_in[2];       // [8,2048]
  const float* Wq = (const float*)d_in[3];
  const float* bq = (const float*)d_in[4];
  const float* Wk = (const float*)d_in[5];
  const float* bk = (const float*)d_in[6];
  const float* Wv = (const float*)d_in[7];
  const float* bv = (const float*)d_in[8];
  const float* Wo = (const float*)d_in[9];
  const float* bo = (const float*)d_in[10];
  float* out = (float*)d_out;

  char* ws = (char*)d_ws;
  size_t off = 0;
  auto alloc = [&](size_t bytes) {
    char* p = ws + off;
    off += (bytes + 255) & ~(size_t)255;
    return p;
  };
  bf16* qb  = (bf16*)alloc(8192ull * 1024 * 2);
  bf16* kvb = (bf16*)alloc(16384ull * 1024 * 2);
  bf16* WqT = (bf16*)alloc(1024ull * 1024 * 2);
  bf16* WkT = (bf16*)alloc(1024ull * 1024 * 2);
  bf16* WvT = (bf16*)alloc(1024ull * 1024 * 2);
  bf16* WoT = (bf16*)alloc(1024ull * 1024 * 2);
  bf16* Qb  = (bf16*)alloc(8192ull * 1024 * 2);
  bf16* Kb  = (bf16*)alloc(16384ull * 1024 * 2);
  bf16* VT  = (bf16*)alloc(8192ull * 2048 * 2);
  bf16* S   = (bf16*)alloc(8ull * 1024 * 2048 * 2);
  bf16* Cb = Qb;  // alias: Qb dead after scores GEMM

  // 1. conversions / weight prep
  cvt2_f32_bf16<<<24576, 256, 0, stream>>>(
      query, qb, 8192ll * 1024 / 4, key_value, kvb, 16384ll * 1024 / 4);
  transpose4_f32_to_bf16<<<dim3(32, 32, 4), 256, 0, stream>>>(
      Wq, Wk, Wv, Wo, WqT, WkT, WvT, WoT);

  // 2. Q projection (128x64 tiles, grid 1024 -> 4 blocks/CU)
  gemm_bt<bf16, 1, 2, 64><<<1024, 256, 0, stream>>>(
      qb, WqT, Qb, bq, 1.f, 1024, 1024, 1024, 1024, 16, 0, 0, 0);

  // 3. K projection (128x128, grid 1024)
  gemm_bt<bf16, 1, 2, 128><<<1024, 256, 0, stream>>>(
      kvb, WkT, Kb, bk, 1.f, 1024, 1024, 1024, 1024, 8, 0, 0, 0);

  // 4. V^T projection (direct, 128x128, grid 1024, row bias):
  //    VT[b][h][s] = sum_d WvT[h][d]*kv[b][s][d] + bv[h]
  gemm_bt<bf16, 2, 1, 128><<<1024, 256, 0, stream>>>(
      WvT, kvb, VT, bv, 1.f, 1024, 1024, 1024, 2048, 16,
      0, 2048ll * 1024, 1024ll * 2048);

  // 5. scores (128x128, grid 1024): S = (Q @ K^T)/32, batch->XCD pinned
  gemm_bt<bf16, 0, 1, 128><<<1024, 256, 0, stream>>>(
      Qb, Kb, S, nullptr, 0.03125f, 1024, 1024, 1024, 2048, 16,
      1024ll * 1024, 2048ll * 1024, 1024ll * 2048);

  // 6. masked softmax in-place -> P
  softmax_mask<<<8192, 256, 0, stream>>>(S, key_mask);

  // 7. context = P @ V (128x64, grid 1024, batch->XCD pinned)
  gemm_bt<bf16, 0, 1, 64><<<1024, 256, 0, stream>>>(
      S, VT, Cb, nullptr, 1.f, 2048, 2048, 2048, 1024, 16,
      1024ll * 2048, 1024ll * 2048, 1024ll * 1024);

  // 8. out = Cb @ Wo + bo (128x64, grid 1024, f32)
  gemm_bt<float, 1, 2, 64><<<1024, 256, 0, stream>>>(
      Cb, WoT, out, bo, 1.f, 1024, 1024, 1024, 1024, 16, 0, 0, 0);
}

// Round 9
// 223.224 us; speedup vs baseline: 1.3911x; 1.2783x over previous
//
#include <hip/hip_runtime.h>
#include <hip/hip_bf16.h>

typedef __hip_bfloat16 bf16;
typedef float f32x4 __attribute__((ext_vector_type(4)));
typedef short s16x8 __attribute__((ext_vector_type(8)));

// ---------------------------------------------------------------------------
__device__ __forceinline__ void async_load16(const void* g, void* lds) {
  __builtin_amdgcn_global_load_lds(
      (const __attribute__((address_space(1))) void*)g,
      (__attribute__((address_space(3))) void*)lds, 16, 0, 0);
}

__device__ __forceinline__ void store_out(float* p, float v) { *p = v; }
__device__ __forceinline__ void store_out(bf16* p, float v) { *p = __float2bfloat16(v); }

// ---------------------------------------------------------------------------
// C[M,N] = scale*(A[M,K] @ BT[N,K]^T) (+epilogue). bf16 in, f32 acc.
// 128xBN tile, BK=32, 4 waves, 2-phase dbuf prefetch (r5-proven structure).
// BIASMODE: 0 none, 1 col-bias, 2 row-bias, 3 exp(scale*acc) masked to col<nv,
//           4 divide by rowsum (biasp = sums, per-batch offset bz*1024).
// SWZ: 1 batched (id&7=batch, XCD pin), 2 chunked XCD swizzle.
// VAR: 0 none, 1 skip M-tiles >= ceil128(nv), 2 skip N-tiles >= ceil128(nv),
//      3 K-loop count = ceil32(nv).
template <typename OutT, int BIASMODE, int SWZ, int BN, int VAR>
__global__ void gemm_bt(const bf16* __restrict__ Ag, const bf16* __restrict__ Bg,
                        OutT* Cg, const float* __restrict__ biasp,
                        const int* __restrict__ nvalid, float scale,
                        int K, int lda, int ldb, int ldc, int ntx,
                        long long sA, long long sB, long long sC) {
  constexpr int NFR = BN / 32;      // n-frags per wave (waves 2x2; wave N = BN/2)
  constexpr int BCH = BN / 64;      // B staging chunks per thread
  __shared__ bf16 As[2][128 * 32];
  __shared__ bf16 Bs[2][BN * 32];

  const int id = blockIdx.x;
  int bz = 0, tile;
  if (SWZ == 1) { bz = id & 7; tile = id >> 3; }
  else { const int q = gridDim.x >> 3; tile = (id & 7) * q + (id >> 3); }
  const int tn = tile % ntx, tm = tile / ntx;

  int nv = 0;
  if (VAR != 0 || BIASMODE == 3) nv = nvalid[bz];
  if (VAR == 1 && tm * 128 >= ((nv + 127) & ~127)) return;
  if (VAR == 2 && tn * BN >= ((nv + 127) & ~127)) return;
  const int nt = (VAR == 3) ? ((nv + 31) >> 5) : (K >> 5);

  const bf16* A = Ag + bz * sA;
  const bf16* BT = Bg + bz * sB;
  OutT* C = Cg + bz * sC;

  const int t = threadIdx.x;
  const int lane = t & 63;
  const int wid = t >> 6;
  const int wr = wid >> 1, wc = wid & 1;
  const int lo = lane & 15, hi = lane >> 4;

  const int arow0 = tm * 128, brow0 = tn * BN;

  const int idx0 = t, idx1 = 256 + t;
  const int r0 = idx0 >> 2, c0 = (idx0 & 3) * 8;
  const int r1 = idx1 >> 2, c1 = (idx1 & 3) * 8;
  const bf16* a0 = A + (long long)(arow0 + r0) * lda + c0;
  const bf16* a1 = A + (long long)(arow0 + r1) * lda + c1;
  const bf16* b0 = BT + (long long)(brow0 + r0) * ldb + c0;
  const bf16* b1 = BT + (long long)(brow0 + r1) * ldb + c1;

  f32x4 acc[4][NFR] = {};

  // prologue: stage tile 0
  async_load16(a0, &As[0][idx0 * 8]);
  async_load16(a1, &As[0][idx1 * 8]);
  async_load16(b0, &Bs[0][idx0 * 8]);
  if (BCH == 2) async_load16(b1, &Bs[0][idx1 * 8]);
  __syncthreads();

  int cur = 0;
  for (int kt = 0; kt < nt; ++kt) {
    const int nxt = cur ^ 1;
    if (kt + 1 < nt) {
      const int k0 = (kt + 1) << 5;
      async_load16(a0 + k0, &As[nxt][idx0 * 8]);
      async_load16(a1 + k0, &As[nxt][idx1 * 8]);
      async_load16(b0 + k0, &Bs[nxt][idx0 * 8]);
      if (BCH == 2) async_load16(b1 + k0, &Bs[nxt][idx1 * 8]);
    }
    s16x8 a[4], b[NFR];
#pragma unroll
    for (int m = 0; m < 4; ++m)
      a[m] = *(const s16x8*)&As[cur][(wr * 64 + m * 16 + lo) * 32 + hi * 8];
#pragma unroll
    for (int n = 0; n < NFR; ++n)
      b[n] = *(const s16x8*)&Bs[cur][(wc * (BN / 2) + n * 16 + lo) * 32 + hi * 8];
#pragma unroll
    for (int m = 0; m < 4; ++m)
#pragma unroll
      for (int n = 0; n < NFR; ++n)
        acc[m][n] = __builtin_amdgcn_mfma_f32_16x16x32_bf16(a[m], b[n], acc[m][n], 0, 0, 0);
    __syncthreads();
    cur = nxt;
  }

  // ---- epilogue. C/D layout: col = lane&15, row = (lane>>4)*4 + reg
  float bcol[NFR];
#pragma unroll
  for (int n = 0; n < NFR; ++n) bcol[n] = 0.f;
  if (BIASMODE == 1) {
#pragma unroll
    for (int n = 0; n < NFR; ++n)
      bcol[n] = biasp[brow0 + wc * (BN / 2) + n * 16 + lo];
  }
  const float* srow = (BIASMODE == 4) ? (biasp + bz * 1024) : nullptr;
#pragma unroll
  for (int m = 0; m < 4; ++m) {
    const int row = arow0 + wr * 64 + m * 16 + hi * 4;
    float br[4] = {0.f, 0.f, 0.f, 0.f};
    if (BIASMODE == 2) {
      float4 t4 = *(const float4*)&biasp[row];
      br[0] = t4.x; br[1] = t4.y; br[2] = t4.z; br[3] = t4.w;
    }
    float inv[4] = {1.f, 1.f, 1.f, 1.f};
    if (BIASMODE == 4) {
      float4 s4 = *(const float4*)&srow[row];
      inv[0] = 1.f / s4.x; inv[1] = 1.f / s4.y; inv[2] = 1.f / s4.z; inv[3] = 1.f / s4.w;
    }
#pragma unroll
    for (int n = 0; n < NFR; ++n) {
      const int col = brow0 + wc * (BN / 2) + n * 16 + lo;
#pragma unroll
      for (int j = 0; j < 4; ++j) {
        float v;
        if (BIASMODE == 3)      v = (col < nv) ? __expf(acc[m][n][j] * scale) : 0.f;
        else if (BIASMODE == 4) v = acc[m][n][j] * inv[j];
        else                    v = acc[m][n][j] * scale + bcol[n] + br[j];
        store_out(&C[(long long)(row + j) * ldc + col], v);
      }
    }
  }
}

// ---------------------------------------------------------------------------
// stable compaction of unmasked key indices; one block per batch.
__global__ void compact_mask(const int* __restrict__ mask, int* __restrict__ cidx,
                             int* __restrict__ nvalid) {
  const int b = blockIdx.x;
  const int* m = mask + b * 2048;
  int* ci = cidx + b * 2048;
  const int t = threadIdx.x;
  __shared__ int cnt[256];
  __shared__ int base[256];
  __shared__ int tot;
  int mv[8], c = 0;
#pragma unroll
  for (int j = 0; j < 8; ++j) { mv[j] = m[t * 8 + j]; c += (mv[j] != 0); }
  cnt[t] = c;
  __syncthreads();
  if (t == 0) {
    int s = 0;
    for (int i = 0; i < 256; ++i) { base[i] = s; s += cnt[i]; }
    tot = s;
    nvalid[b] = s;
  }
  __syncthreads();
  int o = base[t];
#pragma unroll
  for (int j = 0; j < 8; ++j)
    if (mv[j]) ci[o++] = t * 8 + j;
  (void)tot;
}

// gathered f32->bf16 conversion of key_value rows into compacted kvc.
// rows [nvalid, ceil128(nvalid)) duplicate the last valid row (finite pad).
__global__ void cvt_kv_gather(const float* __restrict__ kv, const int* __restrict__ cidx,
                              const int* __restrict__ nvalid, bf16* __restrict__ kvc) {
  const int b = blockIdx.y;
  const int s = blockIdx.x;
  const int nv = nvalid[b];
  if (s >= ((nv + 127) & ~127)) return;
  const int src = cidx[b * 2048 + min(s, nv - 1)];
  const float4 v = reinterpret_cast<const float4*>(
      kv + ((long long)b * 2048 + src) * 1024)[threadIdx.x];
  union { bf16 h[4]; unsigned long long u; } cv;
  cv.h[0] = __float2bfloat16(v.x);
  cv.h[1] = __float2bfloat16(v.y);
  cv.h[2] = __float2bfloat16(v.z);
  cv.h[3] = __float2bfloat16(v.w);
  reinterpret_cast<unsigned long long*>(
      kvc + ((long long)b * 2048 + s) * 1024)[threadIdx.x] = cv.u;
}

__global__ void cvt_f32_bf16(const float* __restrict__ in, bf16* __restrict__ out,
                             long long n4) {
  long long i = (long long)blockIdx.x * 256 + threadIdx.x;
  if (i >= n4) return;
  float4 v = reinterpret_cast<const float4*>(in)[i];
  union { bf16 h[4]; unsigned long long u; } cv;
  cv.h[0] = __float2bfloat16(v.x);
  cv.h[1] = __float2bfloat16(v.y);
  cv.h[2] = __float2bfloat16(v.z);
  cv.h[3] = __float2bfloat16(v.w);
  reinterpret_cast<unsigned long long*>(out)[i] = cv.u;
}

__global__ void transpose4_f32_to_bf16(const float* __restrict__ W0, const float* __restrict__ W1,
                                       const float* __restrict__ W2, const float* __restrict__ W3,
                                       bf16* __restrict__ O0, bf16* __restrict__ O1,
                                       bf16* __restrict__ O2, bf16* __restrict__ O3) {
  const float* in; bf16* out;
  switch (blockIdx.z) {
    case 0: in = W0; out = O0; break;
    case 1: in = W1; out = O1; break;
    case 2: in = W2; out = O2; break;
    default: in = W3; out = O3; break;
  }
  __shared__ float tile[32][33];
  const int bx = blockIdx.x * 32, by = blockIdx.y * 32;
  const int tx = threadIdx.x & 31, ty = threadIdx.x >> 5;
#pragma unroll
  for (int i = 0; i < 32; i += 8)
    tile[ty + i][tx] = in[(long long)(by + ty + i) * 1024 + bx + tx];
  __syncthreads();
#pragma unroll
  for (int i = 0; i < 32; i += 8)
    out[(long long)(bx + ty + i) * 1024 + by + tx] = __float2bfloat16(tile[tx][ty + i]);
}

// ---------------------------------------------------------------------------
// sums[row] = sum over cols < ceil32(nv) of P~[row][col]. one block per row.
__global__ void rowsum_p(const bf16* __restrict__ P, const int* __restrict__ nvalid,
                         float* __restrict__ sums) {
  const int row = blockIdx.x;  // b*1024 + q
  const int b = row >> 10;
  const int t32 = (nvalid[b] + 31) & ~31;
  const bf16* p = P + (long long)row * 2048;
  const int t = threadIdx.x;
  const int lane = t & 63, wid = t >> 6;
  float s = 0.f;
  if (t * 8 < t32) {
    s16x8 v = reinterpret_cast<const s16x8*>(p)[t];
    union { s16x8 v; bf16 h[8]; } u;
    u.v = v;
#pragma unroll
    for (int j = 0; j < 8; ++j) s += __bfloat162float(u.h[j]);
  }
  for (int off = 32; off; off >>= 1) s += __shfl_xor(s, off, 64);
  __shared__ float red[4];
  if (lane == 0) red[wid] = s;
  __syncthreads();
  if (t == 0) sums[row] = red[0] + red[1] + red[2] + red[3];
}

// ---------------------------------------------------------------------------
extern "C" void kernel_launch(void* const* d_in, const int* in_sizes, int n_in,
                              void* d_out, int out_size, void* d_ws, size_t ws_size,
                              hipStream_t stream) {
  const float* query = (const float*)d_in[0];      // [8,1024,1024]
  const float* key_value = (const float*)d_in[1];  // [8,2048,1024]
  const int* key_mask = (const int*)d_in[2];       // [8,2048]
  const float* Wq = (const float*)d_in[3];
  const float* bq = (const float*)d_in[4];
  const float* Wk = (const float*)d_in[5];
  const float* bk = (const float*)d_in[6];
  const float* Wv = (const float*)d_in[7];
  const float* bv = (const float*)d_in[8];
  const float* Wo = (const float*)d_in[9];
  const float* bo = (const float*)d_in[10];
  float* out = (float*)d_out;

  char* ws = (char*)d_ws;
  size_t off = 0;
  auto alloc = [&](size_t bytes) {
    char* p = ws + off;
    off += (bytes + 255) & ~(size_t)255;
    return p;
  };
  bf16* qb   = (bf16*)alloc(8192ull * 1024 * 2);     // query bf16
  bf16* kvc  = (bf16*)alloc(16384ull * 1024 * 2);    // compacted kv bf16
  bf16* WqT  = (bf16*)alloc(1024ull * 1024 * 2);
  bf16* WkT  = (bf16*)alloc(1024ull * 1024 * 2);
  bf16* WvT  = (bf16*)alloc(1024ull * 1024 * 2);
  bf16* WoT  = (bf16*)alloc(1024ull * 1024 * 2);
  bf16* Qb   = (bf16*)alloc(8192ull * 1024 * 2);     // later: Cb
  bf16* Kb   = (bf16*)alloc(16384ull * 1024 * 2);    // compacted K proj
  bf16* VT   = (bf16*)alloc(8192ull * 2048 * 2);     // compacted V^T [8][1024][2048]
  bf16* P    = (bf16*)alloc(8ull * 1024 * 2048 * 2); // unnormalized exp scores
  int*  cidx = (int*)alloc(8 * 2048 * 4);
  int*  nval = (int*)alloc(8 * 4);
  float* sums = (float*)alloc(8192 * 4);
  bf16* Cb = Qb;  // alias: Qb dead after scores GEMM

  // 1. compaction + conversions + weight prep
  compact_mask<<<8, 256, 0, stream>>>(key_mask, cidx, nval);
  cvt_f32_bf16<<<8192, 256, 0, stream>>>(query, qb, 8192ll * 1024 / 4);
  cvt_kv_gather<<<dim3(2048, 8), 256, 0, stream>>>(key_value, cidx, nval, kvc);
  transpose4_f32_to_bf16<<<dim3(32, 32, 4), 256, 0, stream>>>(
      Wq, Wk, Wv, Wo, WqT, WkT, WvT, WoT);

  // 2. Q projection (full): [8192,1024] @ Wq + bq -> Qb
  gemm_bt<bf16, 1, 2, 64, 0><<<1024, 256, 0, stream>>>(
      qb, WqT, Qb, bq, nullptr, 1.f, 1024, 1024, 1024, 1024, 16, 0, 0, 0);

  // 3. K projection (compacted rows, skip M-tiles >= ceil128(nv)):
  gemm_bt<bf16, 1, 1, 128, 1><<<1024, 256, 0, stream>>>(
      kvc, WkT, Kb, bk, nval, 1.f, 1024, 1024, 1024, 1024, 8,
      2048ll * 1024, 0, 2048ll * 1024);

  // 4. V^T projection (compacted cols, skip N-tiles, row bias):
  //    VT[b][h][s'] = sum_d WvT[h][d]*kvc[b][s'][d] + bv[h]
  gemm_bt<bf16, 2, 1, 128, 2><<<1024, 256, 0, stream>>>(
      WvT, kvc, VT, bv, nval, 1.f, 1024, 1024, 1024, 2048, 16,
      0, 2048ll * 1024, 1024ll * 2048);

  // 5. scores (compacted cols): P~ = exp((Q @ K'^T)/32), 0 for col >= nv
  gemm_bt<bf16, 3, 1, 128, 2><<<1024, 256, 0, stream>>>(
      Qb, Kb, P, nullptr, nval, 0.03125f, 1024, 1024, 1024, 2048, 16,
      1024ll * 1024, 2048ll * 1024, 1024ll * 2048);

  // 6. row sums of P~
  rowsum_p<<<8192, 256, 0, stream>>>(P, nval, sums);

  // 7. context = (P~ @ V') / rowsum  (var-K = ceil32(nv))
  gemm_bt<bf16, 4, 1, 64, 3><<<1024, 256, 0, stream>>>(
      P, VT, Cb, sums, nval, 1.f, 2048, 2048, 2048, 1024, 16,
      1024ll * 2048, 1024ll * 2048, 1024ll * 1024);

  // 8. out = Cb @ Wo + bo (full, f32)
  gemm_bt<float, 1, 2, 64, 0><<<1024, 256, 0, stream>>>(
      Cb, WoT, out, bo, nullptr, 1.f, 1024, 1024, 1024, 1024, 16, 0, 0, 0);
}